// Round 11
// baseline (282.962 us; speedup 1.0000x reference)
//
#include <hip/hip_runtime.h>
#include <math.h>

#define BB 16
#define TT 4096
#define DD 1024
#define HH 32
#define TCHUNK 64
#define NCHUNK (TT / TCHUNK)   // 64

static constexpr float kEPS = 1e-6f;

typedef float f32x4 __attribute__((ext_vector_type(4)));

// ---------------- Kernel 1: masked partial sums, PLANE-SPLIT ----------------
// grid: (NCHUNK, B, 2), 256 threads; thread owns 4 consecutive d.
// blockIdx.z picks the plane -> each thread runs ONE read stream (the topology
// that won in K3 at R10). Mask re-read per plane is +256KB total (negligible).
__global__ __launch_bounds__(256) void reduce_kernel(
    const float* __restrict__ zr, const float* __restrict__ zi,
    const float* __restrict__ mask,
    float* __restrict__ partR, float* __restrict__ partI,
    float* __restrict__ cntP) {
  const int c = blockIdx.x;
  const int b = blockIdx.y;
  const int p = blockIdx.z;
  const int tid = threadIdx.x;
  const int d4 = tid * 4;

  f32x4 acc = (f32x4)(0.f);
  float msum = 0.f;

  const size_t base = ((size_t)b * TT + (size_t)c * TCHUNK) * DD + d4;
  const float* src = (p ? zi : zr) + base;
  const float* mp = mask + (size_t)b * TT + (size_t)c * TCHUNK;

  #pragma unroll 8
  for (int t = 0; t < TCHUNK; ++t) {
    const float m = mp[t];
    msum += m;
    f32x4 v = *(const f32x4*)(src + (size_t)t * DD);
    acc += v * m;
  }

  const size_t po = ((size_t)c * BB + b) * DD + d4;
  float* part = p ? partI : partR;
  *(f32x4*)(part + po) = acc;
  if (tid == 0 && p == 0) cntP[c * BB + b] = msum;
}

// ---------------- Kernel 2: reduce partials + per-(b,d) MLP ----------------
// (R4-exact: 64 blocks x 256 threads)
__global__ __launch_bounds__(256) void mlp_kernel(
    const float* __restrict__ partR, const float* __restrict__ partI,
    const float* __restrict__ cntP,
    const float* __restrict__ W1m, const float* __restrict__ b1m,
    const float* __restrict__ W2m, const float* __restrict__ b2m,
    const float* __restrict__ W1p, const float* __restrict__ b1p,
    const float* __restrict__ W2p, const float* __restrict__ b2p,
    const float* __restrict__ mag_scale,
    float* __restrict__ anR, float* __restrict__ anI) {
  const int i = blockIdx.x * blockDim.x + threadIdx.x;
  const int b = i >> 10;   // D = 1024
  const int d = i & (DD - 1);

  __shared__ float cntS;
  if (threadIdx.x == 0) {
    float s = 0.f;
    for (int c = 0; c < NCHUNK; ++c) s += cntP[c * BB + b];
    cntS = s;
  }
  __syncthreads();

  float sR = 0.f, sI = 0.f;
  for (int c = 0; c < NCHUNK; ++c) {
    const size_t po = ((size_t)c * BB + b) * DD + d;
    sR += partR[po];
    sI += partI[po];
  }

  const float count = fmaxf(cntS, 1.0f);
  const float Ar = sR / count;
  const float Ai = sI / count;
  const float mag = sqrtf(Ar * Ar + Ai * Ai);
  const float log_mag = logf(mag + kEPS);
  const float inv_me = 1.0f / (mag + kEPS);
  const float pr = Ar * inv_me;
  const float pi = Ai * inv_me;

  float md = b2m[0];
  #pragma unroll
  for (int j = 0; j < HH; ++j) {
    float h = log_mag * W1m[j] + b1m[j];
    h = 0.5f * h * (1.0f + erff(h * 0.70710678118654752440f));
    md += h * W2m[j];
  }
  const float lmo = log_mag + mag_scale[0] * md;

  float pv0 = b2p[0];
  float pv1 = b2p[1];
  #pragma unroll
  for (int j = 0; j < HH; ++j) {
    float hp = pr * W1p[2 * j] + pi * W1p[2 * j + 1] + b1p[j];
    hp = 0.5f * hp * (1.0f + erff(hp * 0.70710678118654752440f));
    pv0 += hp * W2p[j];       // W2p[0][j]
    pv1 += hp * W2p[HH + j];  // W2p[1][j]
  }
  const float nrm = fmaxf(sqrtf(pv0 * pv0 + pv1 * pv1), 1e-12f);
  const float r_out = expf(lmo);
  anR[i] = r_out * pv0 / nrm;
  anI[i] = r_out * pv1 / nrm;
}

// ---------------- Kernel 3: broadcast add, PLANE-SPLIT (R10-exact) ----------
__global__ __launch_bounds__(256) void add_kernel(
    const float* __restrict__ zr, const float* __restrict__ zi,
    const float* __restrict__ anR, const float* __restrict__ anI,
    float* __restrict__ out) {
  const int c = blockIdx.x;
  const int b = blockIdx.y;
  const int p = blockIdx.z;
  const int tid = threadIdx.x;
  const int d4 = tid * 4;

  const int o = b * DD + d4;
  const f32x4 a4 = p ? *(const f32x4*)(anI + o) : *(const f32x4*)(anR + o);

  const size_t base = ((size_t)b * TT + (size_t)c * TCHUNK) * DD + d4;
  const float* src = (p ? zi : zr) + base;
  float* dst = out + (size_t)p * BB * TT * DD + base;

  #pragma unroll 8
  for (int t = TCHUNK - 1; t >= 0; --t) {
    const size_t ro = (size_t)t * DD;
    f32x4 v = __builtin_nontemporal_load((const f32x4*)(src + ro));
    v += a4;
    __builtin_nontemporal_store(v, (f32x4*)(dst + ro));
  }
}

extern "C" void kernel_launch(void* const* d_in, const int* in_sizes, int n_in,
                              void* d_out, int out_size, void* d_ws, size_t ws_size,
                              hipStream_t stream) {
  const float* zr = (const float*)d_in[0];
  const float* zi = (const float*)d_in[1];
  const float* mask = (const float*)d_in[2];
  const float* W1m = (const float*)d_in[3];
  const float* b1m = (const float*)d_in[4];
  const float* W2m = (const float*)d_in[5];
  const float* b2m = (const float*)d_in[6];
  const float* W1p = (const float*)d_in[7];
  const float* b1p = (const float*)d_in[8];
  const float* W2p = (const float*)d_in[9];
  const float* b2p = (const float*)d_in[10];
  const float* mag_scale = (const float*)d_in[11];

  float* ws = (float*)d_ws;
  float* partR = ws;                       // NCHUNK*B*D = 1048576
  float* partI = ws + 1048576;             // 1048576
  float* cntP  = ws + 2097152;             // NCHUNK*B = 1024
  float* anR   = ws + 2098176;             // 16384
  float* anI   = ws + 2114560;             // 16384

  dim3 g1(NCHUNK, BB, 2);
  reduce_kernel<<<g1, 256, 0, stream>>>(zr, zi, mask, partR, partI, cntP);

  mlp_kernel<<<BB * DD / 256, 256, 0, stream>>>(
      partR, partI, cntP, W1m, b1m, W2m, b2m, W1p, b1p, W2p, b2p, mag_scale,
      anR, anI);

  dim3 g3(NCHUNK, BB, 2);
  add_kernel<<<g3, 256, 0, stream>>>(zr, zi, anR, anI, (float*)d_out);
}

// Round 12
// 271.489 us; speedup vs baseline: 1.0423x; 1.0423x over previous
//
#include <hip/hip_runtime.h>
#include <math.h>

#define BB 16
#define TT 4096
#define DD 1024
#define HH 32
#define TCHUNK 64
#define NCHUNK (TT / TCHUNK)   // 64

static constexpr float kEPS = 1e-6f;

typedef float f32x4 __attribute__((ext_vector_type(4)));

// ---------------- Kernel 1: masked partial sums over T (R10/R4-exact) -------
// grid: (NCHUNK, B), 256 threads; thread owns 4 consecutive d (256*4 = D).
__global__ __launch_bounds__(256) void reduce_kernel(
    const float* __restrict__ zr, const float* __restrict__ zi,
    const float* __restrict__ mask,
    float* __restrict__ partR, float* __restrict__ partI,
    float* __restrict__ cntP) {
  const int c = blockIdx.x;
  const int b = blockIdx.y;
  const int tid = threadIdx.x;
  const int d4 = tid * 4;

  f32x4 accR = (f32x4)(0.f);
  f32x4 accI = (f32x4)(0.f);
  float msum = 0.f;

  const size_t base = ((size_t)b * TT + (size_t)c * TCHUNK) * DD + d4;
  const float* zrp = zr + base;
  const float* zip = zi + base;
  const float* mp = mask + (size_t)b * TT + (size_t)c * TCHUNK;

  #pragma unroll 8
  for (int t = 0; t < TCHUNK; ++t) {
    const float m = mp[t];
    msum += m;
    f32x4 r  = *(const f32x4*)(zrp + (size_t)t * DD);
    f32x4 im = *(const f32x4*)(zip + (size_t)t * DD);
    accR += r * m;
    accI += im * m;
  }

  const size_t po = ((size_t)c * BB + b) * DD + d4;
  *(f32x4*)(partR + po) = accR;
  *(f32x4*)(partI + po) = accI;
  if (tid == 0) cntP[c * BB + b] = msum;
}

// ---------------- Kernel 2: cooperative reduce + per-(b,d) MLP --------------
// grid: 256 blocks x 256 threads. Block = (b, 64-d slice). 4 threads per d,
// each sums 16 chunks (coalesced: lanes read consecutive d); LDS reduce 4->1;
// then threads with cs==0 each run ONE MLP (low VGPR; R9 lesson).
__global__ __launch_bounds__(256) void mlp_kernel(
    const float* __restrict__ partR, const float* __restrict__ partI,
    const float* __restrict__ cntP,
    const float* __restrict__ W1m, const float* __restrict__ b1m,
    const float* __restrict__ W2m, const float* __restrict__ b2m,
    const float* __restrict__ W1p, const float* __restrict__ b1p,
    const float* __restrict__ W2p, const float* __restrict__ b2p,
    const float* __restrict__ mag_scale,
    float* __restrict__ anR, float* __restrict__ anI) {
  const int b = blockIdx.x >> 4;
  const int d0 = (blockIdx.x & 15) * 64;
  const int dl = threadIdx.x & 63;   // local d
  const int cs = threadIdx.x >> 6;   // chunk segment 0..3
  const int d = d0 + dl;

  float sR = 0.f, sI = 0.f;
  #pragma unroll
  for (int k = 0; k < 16; ++k) {
    const int c = cs * 16 + k;
    const size_t po = ((size_t)c * BB + b) * DD + d;
    sR += partR[po];
    sI += partI[po];
  }

  __shared__ float redR[4][64];
  __shared__ float redI[4][64];
  __shared__ float cntRed[64];
  redR[cs][dl] = sR;
  redI[cs][dl] = sI;
  if (threadIdx.x < NCHUNK) cntRed[threadIdx.x] = cntP[threadIdx.x * BB + b];
  __syncthreads();

  if (cs == 0) {
    sR = redR[0][dl] + redR[1][dl] + redR[2][dl] + redR[3][dl];
    sI = redI[0][dl] + redI[1][dl] + redI[2][dl] + redI[3][dl];
    float count = 0.f;
    #pragma unroll
    for (int c = 0; c < NCHUNK; ++c) count += cntRed[c];  // LDS broadcast reads
    count = fmaxf(count, 1.0f);

    const float Ar = sR / count;
    const float Ai = sI / count;
    const float mag = sqrtf(Ar * Ar + Ai * Ai);
    const float log_mag = logf(mag + kEPS);
    const float inv_me = 1.0f / (mag + kEPS);
    const float pr = Ar * inv_me;
    const float pi = Ai * inv_me;

    float md = b2m[0];
    #pragma unroll
    for (int j = 0; j < HH; ++j) {
      float h = log_mag * W1m[j] + b1m[j];
      h = 0.5f * h * (1.0f + erff(h * 0.70710678118654752440f));
      md += h * W2m[j];
    }
    const float lmo = log_mag + mag_scale[0] * md;

    float pv0 = b2p[0];
    float pv1 = b2p[1];
    #pragma unroll
    for (int j = 0; j < HH; ++j) {
      float hp = pr * W1p[2 * j] + pi * W1p[2 * j + 1] + b1p[j];
      hp = 0.5f * hp * (1.0f + erff(hp * 0.70710678118654752440f));
      pv0 += hp * W2p[j];       // W2p[0][j]
      pv1 += hp * W2p[HH + j];  // W2p[1][j]
    }
    const float nrm = fmaxf(sqrtf(pv0 * pv0 + pv1 * pv1), 1e-12f);
    const float r_out = expf(lmo);
    const int i = b * DD + d;
    anR[i] = r_out * pv0 / nrm;
    anI[i] = r_out * pv1 / nrm;
  }
}

// ---------------- Kernel 3: broadcast add, PLANE-SPLIT (R10-exact) ----------
__global__ __launch_bounds__(256) void add_kernel(
    const float* __restrict__ zr, const float* __restrict__ zi,
    const float* __restrict__ anR, const float* __restrict__ anI,
    float* __restrict__ out) {
  const int c = blockIdx.x;
  const int b = blockIdx.y;
  const int p = blockIdx.z;
  const int tid = threadIdx.x;
  const int d4 = tid * 4;

  const int o = b * DD + d4;
  const f32x4 a4 = p ? *(const f32x4*)(anI + o) : *(const f32x4*)(anR + o);

  const size_t base = ((size_t)b * TT + (size_t)c * TCHUNK) * DD + d4;
  const float* src = (p ? zi : zr) + base;
  float* dst = out + (size_t)p * BB * TT * DD + base;

  #pragma unroll 8
  for (int t = TCHUNK - 1; t >= 0; --t) {
    const size_t ro = (size_t)t * DD;
    f32x4 v = __builtin_nontemporal_load((const f32x4*)(src + ro));
    v += a4;
    __builtin_nontemporal_store(v, (f32x4*)(dst + ro));
  }
}

extern "C" void kernel_launch(void* const* d_in, const int* in_sizes, int n_in,
                              void* d_out, int out_size, void* d_ws, size_t ws_size,
                              hipStream_t stream) {
  const float* zr = (const float*)d_in[0];
  const float* zi = (const float*)d_in[1];
  const float* mask = (const float*)d_in[2];
  const float* W1m = (const float*)d_in[3];
  const float* b1m = (const float*)d_in[4];
  const float* W2m = (const float*)d_in[5];
  const float* b2m = (const float*)d_in[6];
  const float* W1p = (const float*)d_in[7];
  const float* b1p = (const float*)d_in[8];
  const float* W2p = (const float*)d_in[9];
  const float* b2p = (const float*)d_in[10];
  const float* mag_scale = (const float*)d_in[11];

  float* ws = (float*)d_ws;
  float* partR = ws;                       // NCHUNK*B*D = 1048576
  float* partI = ws + 1048576;             // 1048576
  float* cntP  = ws + 2097152;             // NCHUNK*B = 1024
  float* anR   = ws + 2098176;             // 16384
  float* anI   = ws + 2114560;             // 16384

  dim3 g1(NCHUNK, BB);
  reduce_kernel<<<g1, 256, 0, stream>>>(zr, zi, mask, partR, partI, cntP);

  mlp_kernel<<<256, 256, 0, stream>>>(
      partR, partI, cntP, W1m, b1m, W2m, b2m, W1p, b1p, W2p, b2p, mag_scale,
      anR, anI);

  dim3 g3(NCHUNK, BB, 2);
  add_kernel<<<g3, 256, 0, stream>>>(zr, zi, anR, anI, (float*)d_out);
}